// Round 13
// baseline (1957.821 us; speedup 1.0000x reference)
//
#include <hip/hip_runtime.h>
#include <hip/hip_bf16.h>

#define DEV __device__ __forceinline__

typedef __bf16 bf16x8 __attribute__((ext_vector_type(8)));
typedef float  f32x4  __attribute__((ext_vector_type(4)));
typedef unsigned short u16;

DEV u16   f2b(float f) { __bf16 h = (__bf16)f; return __builtin_bit_cast(u16, h); }
DEV float b2f(u16 x)   { return __builtin_bit_cast(float, ((unsigned)x) << 16); }

DEV void gl_lds16(const u16* g, u16* l) {
  __builtin_amdgcn_global_load_lds((const __attribute__((address_space(1))) void*)g,
                                   (__attribute__((address_space(3))) void*)l, 16, 0, 0);
}

// row map: S>0 -> ((m>>3)*S + j)*8 + (m&7); S==0 -> m; S<0 -> m&7 (replicate)
DEV long arow(int m, int S, int j) {
  if (S > 0)  return ((long)((m >> 3) * S + j)) * 8 + (m & 7);
  if (S == 0) return m;
  return m & 7;
}

// ---------------------------------------------------------------------------
// Unified segment-GEMM, m97-style core: 128x128 tile, BK=64, single-buffered
// 32KB LDS, 4 waves x (4x4 16x16 frags), 2-barrier K-loop.
// mode 0: squaring; mode 2: ph1/ph2; mode 3: ph3 (hall/out0/silu epilogue).
// XCD swizzle only when the z-slice fills the grid (ylim==gridDim.y).
// ---------------------------------------------------------------------------
struct ZCfg {
  const u16 *A0, *A1, *A2, *A3, *A4;
  const u16 *B0, *B1, *B2, *B3, *B4;
  int S0, J0, S1, J1, S2, J2, S3, J3, S4, J4;
  int nseg, mvalid, q, mode, ylim;
  const float* addc;
  const float* addf;
  const u16*   addb; int addS, addJ;
  float* outf;
  u16 *outb, *outbT, *outlo;
  u16* outm; int oS, oJ;
  u16 *glamH, *glamL;
  float *hall, *out0;
};
struct GArgs { ZCfg z0, z1, z2, z3; };

__global__ __launch_bounds__(256) void gU(GArgs ga)
{
  ZCfg c;
  switch (blockIdx.z) { case 0: c = ga.z0; break; case 1: c = ga.z1; break;
                        case 2: c = ga.z2; break; default: c = ga.z3; break; }

  int gx = gridDim.x;
  int fid = blockIdx.y * gx + blockIdx.x;
  int nwg = gx * gridDim.y;
  int idx = (c.ylim == (int)gridDim.y) ? ((fid & 7) * (nwg >> 3) + (fid >> 3))
                                       : fid;
  int mt = idx / gx, et = idx % gx;
  if (mt >= c.ylim) return;
  int m0 = mt << 7, e0 = et << 7;

  const int K = c.nseg << 10;
  int tid = threadIdx.x, lane = tid & 63, w = tid >> 6;
  int wr = (w >> 1) << 6, wc = (w & 1) << 6;   // wave quadrant base (rows/cols)

  __shared__ u16 As[8192], Bs[8192];   // 16KB + 16KB, single buffer
  f32x4 acc[4][4] = {};

  // staging: 16KB tile = [128 rows][128B]; thread covers 4 x 16B
  int rA[4], cA[4];
#pragma unroll
  for (int j = 0; j < 4; ++j) {
    int p = j * 4096 + tid * 16;
    int r = p >> 7, o = (p & 127) ^ ((r & 7) << 4);
    rA[j] = r; cA[j] = o >> 1;
  }
  auto seg = [&](int i, const u16*& A, int& S, int& J, const u16*& B) {
    switch (i) {
      case 0: A = c.A0; S = c.S0; J = c.J0; B = c.B0; break;
      case 1: A = c.A1; S = c.S1; J = c.J1; B = c.B1; break;
      case 2: A = c.A2; S = c.S2; J = c.J2; B = c.B2; break;
      case 3: A = c.A3; S = c.S3; J = c.J3; B = c.B3; break;
      default: A = c.A4; S = c.S4; J = c.J4; B = c.B4; break;
    }
  };
  auto stage = [&](int kt) {
    int si = kt >> 10, kl = kt & 1023;
    const u16 *A, *B; int S, J;
    seg(si, A, S, J, B);
#pragma unroll
    for (int j = 0; j < 4; ++j) {
      int grow = m0 + rA[j];
      gl_lds16(A + arow(grow, S, J) * 1024 + kl + cA[j], &As[j * 2048 + w * 512]);
    }
#pragma unroll
    for (int j = 0; j < 4; ++j)
      gl_lds16(B + (size_t)(e0 + rA[j]) * 1024 + kl + cA[j], &Bs[j * 2048 + w * 512]);
  };

  for (int kt = 0; kt < K; kt += 64) {
    stage(kt);
    asm volatile("s_waitcnt vmcnt(0)" ::: "memory");
    __syncthreads();
#pragma unroll
    for (int ks = 0; ks < 2; ++ks) {
      int oa = ks * 64 + ((lane >> 4) << 4);
      bf16x8 af[4], bf[4];
#pragma unroll
      for (int f = 0; f < 4; ++f) {
        int ra = wr + f * 16 + (lane & 15);
        int rb = wc + f * 16 + (lane & 15);
        af[f] = *(const bf16x8*)((const char*)As + ra * 128 + (oa ^ ((ra & 7) << 4)));
        bf[f] = *(const bf16x8*)((const char*)Bs + rb * 128 + (oa ^ ((rb & 7) << 4)));
      }
#pragma unroll
      for (int ms = 0; ms < 4; ++ms)
#pragma unroll
        for (int ns = 0; ns < 4; ++ns)
          acc[ms][ns] = __builtin_amdgcn_mfma_f32_16x16x32_bf16(af[ms], bf[ns], acc[ms][ns], 0, 0, 0);
    }
    __syncthreads();
  }

  int l4 = ((lane >> 4) << 2), lc = lane & 15;
#pragma unroll
  for (int ms = 0; ms < 4; ++ms)
#pragma unroll
    for (int ns = 0; ns < 4; ++ns)
#pragma unroll
      for (int j = 0; j < 4; ++j) {
        int row = m0 + wr + ms * 16 + l4 + j;   // C/D: row=(lane>>4)*4+reg
        int col = e0 + wc + ns * 16 + lc;       // C/D: col=lane&15
        float v = acc[ms][ns][j];
        if (c.mode == 0) {
          u16 h = f2b(v);
          if (c.outb)  c.outb[(size_t)row * 1024 + col] = h;
          if (c.outbT) c.outbT[(size_t)col * 1024 + row] = h;
        } else if (c.mode == 2) {
          if (c.addc) v += c.addc[col];
          if (c.addb)      v += b2f(c.addb[arow(row, c.addS, c.addJ) * 1024 + col]);
          else if (c.addf) v += c.addf[arow(row, c.addS, c.addJ) * 1024 + col];
          if (row < c.mvalid) {
            if (c.outf) c.outf[(size_t)row * 1024 + col] = v;
            u16 hi = f2b(v);
            if (c.outb)  c.outb[(size_t)row * 1024 + col] = hi;
            if (c.outlo) c.outlo[(size_t)row * 1024 + col] = f2b(v - b2f(hi));
            if (c.outm)  c.outm[arow(row, c.oS, c.oJ) * 1024 + col] = hi;
            if (c.glamH && ((row >> 3) & 15) == 0) {     // fused Lambda_1 gather
              int r2 = ((row >> 3) >> 4) * 8 + (row & 7);
              c.glamH[(size_t)r2 * 1024 + col] = hi;
              c.glamL[(size_t)r2 * 1024 + col] = f2b(v - b2f(hi));
            }
          }
        } else {
          v += b2f(c.addb[arow(row, c.addS, c.addJ) * 1024 + col]);
          int t = (row >> 3) * 4 + c.q, b = row & 7;
          c.hall[(size_t)t * 8192 + b * 1024 + col] = v;
          float sg = 1.f / (1.f + __expf(-v));
          c.out0[(size_t)(t - 1) * 8192 + b * 1024 + col] = v * v * sg;
          if (c.outb) c.outb[(size_t)row * 1024 + col] = f2b(v);
        }
      }
}

// ---- power iteration + misc helpers -----------------------------------------
__global__ void k_init(const float* __restrict__ u_in, const float* __restrict__ h0,
                       float* __restrict__ u_cur, float* __restrict__ v_acc,
                       float* __restrict__ u_acc, float* __restrict__ hall0,
                       u16* __restrict__ bndSb, u16* __restrict__ bndSlo,
                       u16* __restrict__ bndb)
{
  int i = blockIdx.x * 256 + threadIdx.x;
  if (i < 1024) { u_cur[i] = u_in[i]; v_acc[i] = 0.f; u_acc[i] = 0.f; }
  if (i < 8192) {
    float h = h0[i];
    hall0[i] = h;
    u16 hi = f2b(h);
    bndSb[i] = hi;
    bndSlo[i] = f2b(h - b2f(hi));
    bndb[i] = hi;
  }
}

__global__ void k_v(const float* __restrict__ W, const float* __restrict__ u_cur,
                    float* __restrict__ v_acc)
{
  int d = blockIdx.x * 256 + threadIdx.x;
  int e0 = blockIdx.y * 64;
  float a = 0.f;
  for (int e = e0; e < e0 + 64; ++e) a += W[(size_t)e * 1024 + d] * u_cur[e];
  atomicAdd(&v_acc[d], a);
}

__global__ void k_u(const float* __restrict__ W, const float* __restrict__ v_cur,
                    float* __restrict__ u_acc)
{
  int lg = threadIdx.x & 15, ei = threadIdx.x >> 4;
  int e = blockIdx.y * 16 + ei;
  int d0 = blockIdx.x * 512;
  float a = 0.f;
  for (int i = 0; i < 32; ++i) { int d = d0 + lg + 16 * i; a += W[(size_t)e * 1024 + d] * v_cur[d]; }
#pragma unroll
  for (int m = 1; m < 16; m <<= 1) a += __shfl_xor(a, m);
  if (lg == 0) atomicAdd(&u_acc[e], a);
}

__global__ void k_norm(const float* __restrict__ acc, float* __restrict__ outv,
                       float* __restrict__ z1)
{
  __shared__ float red[16];
  int t = threadIdx.x;
  float x = acc[t];
  float ss = x * x;
#pragma unroll
  for (int m = 1; m < 64; m <<= 1) ss += __shfl_xor(ss, m);
  if ((t & 63) == 0) red[t >> 6] = ss;
  __syncthreads();
  if (t < 64) {
    float s = (t < 16) ? red[t] : 0.f;
#pragma unroll
    for (int m = 1; m < 16; m <<= 1) s += __shfl_xor(s, m);
    if (t == 0) red[0] = s;
  }
  __syncthreads();
  float nrm = sqrtf(red[0]) + 1e-8f;
  outv[t] = x / nrm;
  z1[t] = 0.f;
}

__global__ void k_sigma(const float* __restrict__ acc, float* __restrict__ scale)
{
  __shared__ float red[16];
  int t = threadIdx.x;
  float x = acc[t];
  float ss = x * x;
#pragma unroll
  for (int m = 1; m < 64; m <<= 1) ss += __shfl_xor(ss, m);
  if ((t & 63) == 0) red[t >> 6] = ss;
  __syncthreads();
  if (t < 64) {
    float s = (t < 16) ? red[t] : 0.f;
#pragma unroll
    for (int m = 1; m < 16; m <<= 1) s += __shfl_xor(s, m);
    if (t == 0) {
      float sigma = s / (sqrtf(s) + 1e-8f);
      scale[0] = 0.95f / (sigma + 1e-8f);
    }
  }
}

__global__ void k_prep(const float* __restrict__ Wh, const float* __restrict__ Wx,
                       const float* __restrict__ scale, u16* __restrict__ wh_b,
                       u16* __restrict__ whT, u16* __restrict__ wxb)
{
  int i = blockIdx.x * 256 + threadIdx.x;
  float s = scale[0];
  int e = i >> 10, d = i & 1023;
  u16 hw = f2b(Wh[i] * s);
  wh_b[i] = hw;
  whT[(size_t)d * 1024 + e] = hw;
  wxb[i] = f2b(Wx[i]);
}

__global__ void k_cvt(const float* __restrict__ in, u16* __restrict__ out, int n)
{
  int i = (blockIdx.x * 256 + threadIdx.x) * 4;
  if (i >= n) return;
  float4 v = *(const float4*)(in + i);
  ushort4 o;
  o.x = f2b(v.x); o.y = f2b(v.y); o.z = f2b(v.z); o.w = f2b(v.w);
  *(ushort4*)(out + i) = o;
}

static void setseg(ZCfg& z, int i, const u16* A, int S, int J, const u16* B) {
  switch (i) {
    case 0: z.A0 = A; z.S0 = S; z.J0 = J; z.B0 = B; break;
    case 1: z.A1 = A; z.S1 = S; z.J1 = J; z.B1 = B; break;
    case 2: z.A2 = A; z.S2 = S; z.J2 = J; z.B2 = B; break;
    case 3: z.A3 = A; z.S3 = S; z.J3 = J; z.B3 = B; break;
    default: z.A4 = A; z.S4 = S; z.J4 = J; z.B4 = B; break;
  }
}
static void setsq(ZCfg& z, const u16* A, const u16* B, u16* o, u16* oT) {
  z.A0 = A; z.S0 = 0; z.J0 = 0; z.B0 = B; z.nseg = 1;
  z.outb = o; z.outbT = oT; z.mode = 0; z.ylim = 8;
}

extern "C" void kernel_launch(void* const* d_in, const int* in_sizes, int n_in,
                              void* d_out, int out_size, void* d_ws, size_t ws_size,
                              hipStream_t stream)
{
  (void)in_sizes; (void)n_in; (void)out_size; (void)ws_size;
  const float* x  = (const float*)d_in[0];
  const float* h0 = (const float*)d_in[1];
  const float* Wx = (const float*)d_in[2];
  const float* Wh = (const float*)d_in[3];
  const float* bv = (const float*)d_in[4];
  const float* uv = (const float*)d_in[5];

  float* out0 = (float*)d_out;
  float* hall = out0 + 16777216;

  const size_t M1 = 1048576;
  // ---- ws: everything phase 3 reads + small state ----
  char* ws = (char*)d_ws;
  u16*   pre_b = (u16*)(ws);                  // 32 MiB [16384,1024] bf16
  u16*   wh_b  = (u16*)(ws + 32 * M1);        // 2 MiB
  u16*   bnd_b = (u16*)(ws + 34 * M1);        // 8 MiB [4096,1024]
  u16*   lb0   = (u16*)(ws + 42 * M1);        // 8 MiB phase-3 chain
  u16*   bndSb = (u16*)(ws + 50 * M1);        // 512 KiB [256,1024]
  u16*   bndSlo= (u16*)(ws + 50 * M1 + 524288);
  float* u_cur = (float*)(ws + 51 * M1);
  float* v_cur = u_cur + 1024;
  float* v_acc = u_cur + 2048;
  float* u_acc = u_cur + 3072;
  float* scale = u_cur + 4096;
  u16*   W2    = (u16*)(ws + 52 * M1);        // 2 MiB — read by phase 3!

  // ---- hall scratch (HBS = hall + 32 KiB; dead before phase 3) ----
  char* HBS = (char*)hall + 32768;
  u16*   xb   = (u16*)(HBS);                   // 32 MiB (dead after pre-GEMM)
  float* lC   = (float*)(HBS);                 // 16 MiB (over xb)
  u16*   lCb  = (u16*)(HBS + 16 * M1);         // 8 MiB
  float* lamF = (float*)(HBS + 24 * M1);       // 1 MiB
  u16* lamH0  = (u16*)(HBS + 25 * M1);
  u16* lamH1  = (u16*)(HBS + 25 * M1 + 524288);
  u16* lamL0  = (u16*)(HBS + 26 * M1);
  u16* lamL1  = (u16*)(HBS + 26 * M1 + 524288);
  u16* pcH0   = (u16*)(HBS + 27 * M1);
  u16* pcH1   = (u16*)(HBS + 27 * M1 + 524288);
  u16* pcL0   = (u16*)(HBS + 28 * M1);
  u16* pcL1   = (u16*)(HBS + 28 * M1 + 524288);
  auto slot = [&](int k) { return (u16*)(HBS + 32 * M1 + (size_t)k * 2 * M1); };
  u16* whT  = slot(0);   // -> W192 later
  u16* wxb  = slot(1);   // -> W256 later
  u16* W2T  = slot(3);
  u16* W3   = slot(4);
  u16* W4   = slot(5);
  u16* W4T  = slot(6);
  u16* W8   = slot(7);
  u16* W8T  = slot(8);   // -> W128 later
  u16* W12  = slot(9);
  u16* W16  = slot(10);
  u16* W16T = slot(11);  // -> W128T later
  u16* W32  = slot(12);
  u16* W32T = slot(13);
  u16* W64  = slot(14);
  u16* W64T = slot(15);
  u16* W128 = W8T, *W128T = W16T, *W192 = whT, *W256 = wxb;

  k_init<<<32, 256, 0, stream>>>(uv, h0, u_cur, v_acc, u_acc, hall,
                                 bndSb, bndSlo, bnd_b);

  for (int it = 0; it < 3; ++it) {
    k_v<<<dim3(4, 16), 256, 0, stream>>>(Wh, u_cur, v_acc);
    k_norm<<<1, 1024, 0, stream>>>(v_acc, v_cur, u_acc);
    k_u<<<dim3(2, 64), 256, 0, stream>>>(Wh, v_cur, u_acc);
    if (it < 2) k_norm<<<1, 1024, 0, stream>>>(u_acc, u_cur, v_acc);
    else        k_sigma<<<1, 1024, 0, stream>>>(u_acc, scale);
  }
  k_prep<<<4096, 256, 0, stream>>>(Wh, Wx, scale, wh_b, whT, wxb);
  k_cvt<<<16384, 256, 0, stream>>>(x, xb, 16777216);

  // a) pre = x @ Wx^T + b (bf16)  ∥  S1: W2 (-> ws)
  { GArgs a{}; ZCfg& z = a.z0;
    setseg(z, 0, xb, 0, 0, wxb);
    z.nseg = 1; z.mode = 2; z.ylim = 128; z.mvalid = 16384;
    z.addc = bv; z.outb = pre_b;
    setsq(a.z1, wh_b, whT, W2, W2T);
    gU<<<dim3(8, 128, 2), 256, 0, stream>>>(a); }

  // b) S2: W3, W4
  { GArgs a{}; setsq(a.z0, W2, whT, W3, nullptr); setsq(a.z1, W2, W2T, W4, W4T);
    gU<<<dim3(8, 8, 2), 256, 0, stream>>>(a); }

  // c) phase 1 (lC = W3 p0 + W2 p1 + W p2 + p3, gather fused)  ∥  S3: W8
  { GArgs a{}; ZCfg& z = a.z0;
    setseg(z, 0, pre_b, 4, 0, W3);
    setseg(z, 1, pre_b, 4, 1, W2);
    setseg(z, 2, pre_b, 4, 2, wh_b);
    z.nseg = 3; z.mode = 2; z.ylim = 32; z.mvalid = 4096;
    z.addb = pre_b; z.addS = 4; z.addJ = 3;
    z.outf = lC; z.outb = lCb;
    z.glamH = lamH0; z.glamL = lamL0;
    setsq(a.z1, W4, W4T, W8, W8T);
    gU<<<dim3(8, 32, 2), 256, 0, stream>>>(a); }

  // d) S4: W12, W16
  { GArgs a{}; setsq(a.z0, W8, W4T, W12, nullptr); setsq(a.z1, W8, W8T, W16, W16T);
    gU<<<dim3(8, 8, 2), 256, 0, stream>>>(a); }

  // e..h) phase 2a Lambda chain  ∥  S5..S8
  {
    const u16 *chH = lamH0, *chL = lamL0;
    int j0s[3] = {1, 5, 9};
    u16* nxH[3] = { lamH1, lamH0, lamH1 };
    u16* nxL[3] = { lamL1, lamL0, lamL1 };
    const u16* sqA[3] = { W16, W32, W64 };
    const u16* sqB[3] = { W16T, W32T, W64T };
    u16* sqO[3] = { W32, W64, W128 };
    u16* sqT[3] = { W32T, W64T, W128T };
    for (int i = 0; i < 3; ++i) {
      GArgs a{}; ZCfg& z = a.z0;
      setseg(z, 0, chH, 0, 0, W16); setseg(z, 1, chL, 0, 0, W16);
      setseg(z, 2, lCb, 16, j0s[i],     W12);
      setseg(z, 3, lCb, 16, j0s[i] + 1, W8);
      setseg(z, 4, lCb, 16, j0s[i] + 2, W4);
      z.nseg = 5; z.mode = 2; z.ylim = 2; z.mvalid = 256;
      z.addf = lC; z.addS = 16; z.addJ = j0s[i] + 3;
      z.outb = nxH[i]; z.outlo = nxL[i];
      setsq(a.z1, sqA[i], sqB[i], sqO[i], sqT[i]);
      gU<<<dim3(8, 8, 2), 256, 0, stream>>>(a);
      chH = nxH[i]; chL = nxL[i];
    }
    GArgs a{}; ZCfg& z = a.z0;   // Lambda16 final
    setseg(z, 0, chH, 0, 0, W12); setseg(z, 1, chL, 0, 0, W12);
    setseg(z, 2, lCb, 16, 13, W8); setseg(z, 3, lCb, 16, 14, W4);
    z.nseg = 4; z.mode = 2; z.ylim = 2; z.mvalid = 256;
    z.addf = lC; z.addS = 16; z.addJ = 15;
    z.outf = lamF; z.outb = lamH0; z.outlo = lamL0;
    setsq(a.z1, W128, W64T, W192, nullptr);
    setsq(a.z2, W128, W128T, W256, nullptr);
    gU<<<dim3(8, 8, 3), 256, 0, stream>>>(a);
  }

  // i..p) phase 2b: superchunk chain, 8 z-quad launches (M=8)
  {
    const u16* w64s[4] = { W64, W128, W192, W256 };
    for (int sb2 = 0; sb2 < 32; sb2 += 4) {
      int zmax = (sb2 == 28) ? 3 : 4;
      GArgs a{};
      ZCfg* zs[4] = { &a.z0, &a.z1, &a.z2, &a.z3 };
      for (int zz = 1; zz <= zmax; ++zz) {
        ZCfg& z = *zs[zz - 1];
        setseg(z, 0, bndSb + (size_t)sb2 * 8192, -1, 0, w64s[zz - 1]);
        int ns = 1;
        for (int i = 0; i < zz - 1; ++i)
          setseg(z, ns++, lamH0 + (size_t)(sb2 + i) * 8192, -1, 0, w64s[zz - 2 - i]);
        z.nseg = ns; z.mode = 2; z.ylim = 1; z.mvalid = 8;
        z.addf = lamF + (size_t)(sb2 + zz - 1) * 8192; z.addS = -1;
        z.outb = bndSb + (size_t)(sb2 + zz) * 8192;
        z.outlo = bndSlo + (size_t)(sb2 + zz) * 8192;
        z.outm = bnd_b + (size_t)16 * (sb2 + zz) * 8192; z.oS = 0;
      }
      gU<<<dim3(8, 1, zmax), 256, 0, stream>>>(a);
    }
  }

  // q..t) phase 2c: intra-super chunk boundaries, 4 z-quad launches
  {
    const u16* w4s[4] = { W4, W8, W12, W16 };
    const u16* cinH[4] = { bndSb, pcH0, pcH1, pcH0 };
    const u16* cinL[4] = { bndSlo, pcL0, pcL1, pcL0 };
    u16* coutH[4] = { pcH0, pcH1, pcH0, nullptr };
    u16* coutL[4] = { pcL0, pcL1, pcL0, nullptr };
    for (int t4 = 0; t4 < 4; ++t4) {
      int jb = 4 * t4;
      int zmax = (t4 == 3) ? 3 : 4;
      GArgs a{};
      ZCfg* zs[4] = { &a.z0, &a.z1, &a.z2, &a.z3 };
      for (int zz = 1; zz <= zmax; ++zz) {
        ZCfg& z = *zs[zz - 1];
        setseg(z, 0, cinH[t4], 0, 0, w4s[zz - 1]);
        setseg(z, 1, cinL[t4], 0, 0, w4s[zz - 1]);
        int ns = 2;
        for (int i = 0; i < zz - 1; ++i)
          setseg(z, ns++, lCb, 16, jb + i, w4s[zz - 2 - i]);
        z.nseg = ns; z.mode = 2; z.ylim = 2; z.mvalid = 256;
        z.addf = lC; z.addS = 16; z.addJ = jb + zz - 1;
        z.outm = bnd_b; z.oS = 16; z.oJ = jb + zz;
        if (zz == 4) { z.outb = coutH[t4]; z.outlo = coutL[t4]; }
      }
      gU<<<dim3(8, 2, zmax), 256, 0, stream>>>(a);
    }
  }

  // u,v) phase 3: 2 launches, z=2 each: {h1, h2} then {h3, h4}
  {
    const u16* chains[2] = { bnd_b, lb0 };
    u16* chouts[2] = { lb0, nullptr };
    for (int half = 0; half < 2; ++half) {
      int qa = 2 * half + 1;      // 1 or 3
      GArgs a{};
      { ZCfg& z = a.z0;           // h_odd = W * chain + p_even
        setseg(z, 0, chains[half], 0, 0, wh_b);
        z.nseg = 1; z.mode = 3; z.ylim = 32; z.q = qa;
        z.addb = pre_b; z.addS = 4; z.addJ = qa - 1;
        z.hall = hall; z.out0 = out0; }
      { ZCfg& z = a.z1;           // h_even = W2 * chain + W * p_even + p_odd
        setseg(z, 0, chains[half], 0, 0, W2);
        setseg(z, 1, pre_b, 4, qa - 1, wh_b);
        z.nseg = 2; z.mode = 3; z.ylim = 32; z.q = qa + 1;
        z.addb = pre_b; z.addS = 4; z.addJ = qa;
        z.hall = hall; z.out0 = out0;
        z.outb = chouts[half]; }
      gU<<<dim3(8, 32, 2), 256, 0, stream>>>(a);
    }
  }
}

// Round 14
// 982.435 us; speedup vs baseline: 1.9928x; 1.9928x over previous
//
#include <hip/hip_runtime.h>
#include <hip/hip_bf16.h>

#define DEV __device__ __forceinline__

typedef __bf16 bf16x8 __attribute__((ext_vector_type(8)));
typedef float  f32x4  __attribute__((ext_vector_type(4)));
typedef unsigned short u16;

DEV u16   f2b(float f) { __bf16 h = (__bf16)f; return __builtin_bit_cast(u16, h); }
DEV float b2f(u16 x)   { return __builtin_bit_cast(float, ((unsigned)x) << 16); }

DEV void gl_lds16(const u16* g, u16* l) {
  __builtin_amdgcn_global_load_lds((const __attribute__((address_space(1))) void*)g,
                                   (__attribute__((address_space(3))) void*)l, 16, 0, 0);
}

// ---------------------------------------------------------------------------
// Generic 64x64-tile GEMM over virtual K = nseg*1024 (segments of the A
// operand; B is one row-major matrix with stride bstr, columns boff..boff+K).
// BK=128 double-buffered LDS (R4/R7-proven structure). XCD-swizzled block id.
// A segment row map: plain (grow) or pre-time map ((grow>>3)*32+ct)*8+(grow&7).
// MODE 0: PRE  (v+=bias, write pre_b)
// MODE 1: SQ   (write o1 [+o1T] [+Bcat slot o2@o2coff])
// MODE 2: P1   (v+=pre[addct], write chain bf16 [+lC fp32])
// MODE 3: P3   (q=z+1: K=q*1024, boff=(4-q)*1024; v+=pre; write hall/out0,
//               q==4 also chain bf16)
// ---------------------------------------------------------------------------
template<int MODE>
__global__ __launch_bounds__(256) void gK(
    const u16* __restrict__ chain, const u16* __restrict__ preb,
    int ctoff, unsigned aflags, int nseg_a, int boff_a,
    const u16* __restrict__ B, int bstr,
    const float* __restrict__ bias, int addct_a,
    u16* __restrict__ o1, u16* __restrict__ o1T,
    u16* __restrict__ o2, int o2coff,
    float* __restrict__ fout, float* __restrict__ out0, int tbase)
{
  int q = 0, nseg, boff, addct;
  if (MODE == 3) { q = blockIdx.z + 1; nseg = q; boff = (4 - q) << 10; addct = tbase + q - 1; }
  else           { nseg = nseg_a; boff = boff_a; addct = addct_a; }
  const int K = nseg << 10;

  int tid = threadIdx.x, lane = tid & 63, w = tid >> 6;
  int wrow = (w >> 1) << 5, wcol = (w & 1) << 5;

  // XCD-aware bijective swizzle (all grids have gx*gy % 8 == 0, no trimming):
  // each XCD owns a contiguous m-tile range -> A-panel L2 reuse.
  int gx = gridDim.x;
  int fid = blockIdx.y * gx + blockIdx.x;
  int nwg = gx * gridDim.y;
  int idx = (fid & 7) * (nwg >> 3) + (fid >> 3);
  int m0 = (idx / gx) << 6, e0 = (idx % gx) << 6;

  __shared__ u16 As[2][8192], Bs[2][8192];   // 2 x 16KB each = 64KB
  f32x4 acc[2][2] = {};

  int rA[4], cA[4];
#pragma unroll
  for (int j = 0; j < 4; ++j) {
    int p = (j * 4 + w) * 1024 + lane * 16;
    int r = p >> 8, o = (p & 255) ^ ((r & 7) << 4);
    rA[j] = r; cA[j] = o >> 1;
  }
  auto stage = [&](int buf, int kt) {
    int seg = kt >> 10, kl = kt & 1023;
    bool isp = (aflags >> seg) & 1;
    const u16* ap = isp ? preb : chain;
    int ct = ctoff + seg;
#pragma unroll
    for (int j = 0; j < 4; ++j) {
      int grow = m0 + rA[j];
      long ar = isp ? ((long)((grow >> 3) * 32 + ct) * 8 + (grow & 7)) : (long)grow;
      gl_lds16(ap + ar * 1024 + kl + cA[j], &As[buf][(j * 4 + w) * 512]);
    }
#pragma unroll
    for (int j = 0; j < 4; ++j)
      gl_lds16(B + (size_t)(e0 + rA[j]) * bstr + boff + kt + cA[j], &Bs[buf][(j * 4 + w) * 512]);
  };

  stage(0, 0);
  asm volatile("s_waitcnt vmcnt(0)" ::: "memory");
  __syncthreads();

  int buf = 0;
  for (int kt = 0; kt < K; kt += 128, buf ^= 1) {
    if (kt + 128 < K) stage(buf ^ 1, kt + 128);
#pragma unroll
    for (int ks = 0; ks < 4; ++ks) {
      int oa = ks * 64 + ((lane >> 4) << 4);
      bf16x8 af[2], bf[2];
#pragma unroll
      for (int s = 0; s < 2; ++s) {
        int ra = wrow + s * 16 + (lane & 15);
        int rb = wcol + s * 16 + (lane & 15);
        af[s] = *(const bf16x8*)((const char*)&As[buf][0] + ra * 256 + (oa ^ ((ra & 7) << 4)));
        bf[s] = *(const bf16x8*)((const char*)&Bs[buf][0] + rb * 256 + (oa ^ ((rb & 7) << 4)));
      }
#pragma unroll
      for (int ms = 0; ms < 2; ++ms)
#pragma unroll
        for (int ns = 0; ns < 2; ++ns)
          acc[ms][ns] = __builtin_amdgcn_mfma_f32_16x16x32_bf16(af[ms], bf[ns], acc[ms][ns], 0, 0, 0);
    }
    asm volatile("s_waitcnt vmcnt(0)" ::: "memory");
    __syncthreads();
  }

  int l4 = ((lane >> 4) << 2), lc = lane & 15;
#pragma unroll
  for (int ms = 0; ms < 2; ++ms)
#pragma unroll
    for (int ns = 0; ns < 2; ++ns)
#pragma unroll
      for (int j = 0; j < 4; ++j) {
        int row = m0 + wrow + ms * 16 + l4 + j;   // C/D: row=(lane>>4)*4+reg
        int col = e0 + wcol + ns * 16 + lc;       // C/D: col=lane&15
        float v = acc[ms][ns][j];
        if (MODE == 0) {
          v += bias[col];
          o1[(size_t)row * 1024 + col] = f2b(v);
        } else if (MODE == 1) {
          u16 h = f2b(v);
          if (o1)  o1[(size_t)row * 1024 + col] = h;
          if (o1T) o1T[(size_t)col * 1024 + row] = h;
          if (o2)  o2[(size_t)row * 4096 + o2coff + col] = h;
        } else {
          v += b2f(preb[((size_t)((row >> 3) * 32 + addct) * 8 + (row & 7)) * 1024 + col]);
          if (MODE == 2) {
            o1[(size_t)row * 1024 + col] = f2b(v);
            if (fout) fout[(size_t)row * 1024 + col] = v;
          } else {
            int t = (row >> 3) * 32 + tbase + q;
            fout[(size_t)t * 8192 + (row & 7) * 1024 + col] = v;          // h_all[t]
            float sg = 1.f / (1.f + __expf(-v));
            out0[(size_t)(t - 1) * 8192 + (row & 7) * 1024 + col] = v * v * sg;
            if (q == 4) o1[(size_t)row * 1024 + col] = f2b(v);
          }
        }
      }
}

// ---------------------------------------------------------------------------
// Flexible matvec step: out = WA*hin + (WB*adA if WB) + adB ; per-z param set.
// nr64: rows 0..63 with chunk maps; else rows 0..7 identity (pre-offset ptrs).
// ---------------------------------------------------------------------------
__global__ __launch_bounds__(256) void mv_flex(
    const float* hin0, const u16* WA0, const u16* WB0, const float* adA0,
    const float* adB0, float* ho0, u16* hb0, int acA0, int acB0, int bc0,
    const float* hin1, const u16* WA1, const u16* WB1, const float* adA1,
    const float* adB1, float* ho1, u16* hb1, int acA1, int acB1, int bc1,
    int nr64)
{
  int z = blockIdx.z;
  const float* hin = z ? hin1 : hin0;
  const u16*   WA  = z ? WA1  : WA0;
  const u16*   WB  = z ? WB1  : WB0;
  const float* adA = z ? adA1 : adA0;
  const float* adB = z ? adB1 : adB0;
  float* ho = z ? ho1 : ho0;
  u16*   hb = z ? hb1 : hb0;
  int acA = z ? acA1 : acA0, acB = z ? acB1 : acB0, bc = z ? bc1 : bc0;

  int tid = threadIdx.x, lg = tid & 15, eg = tid >> 4;
  int e = blockIdx.x * 16 + eg;
  int r0 = blockIdx.y * 8;
  float acc[8] = {0,0,0,0,0,0,0,0};
  const u16* wra = WA + (size_t)e * 1024;
  const u16* wrb = WB ? WB + (size_t)e * 1024 : nullptr;
#pragma unroll
  for (int i = 0; i < 8; ++i) {
    int d0 = lg * 8 + i * 128;
    ushort4 w0 = *(const ushort4*)(wra + d0);
    ushort4 w1 = *(const ushort4*)(wra + d0 + 4);
    float wa = b2f(w0.x), wb = b2f(w0.y), wc = b2f(w0.z), wd = b2f(w0.w);
    float we_ = b2f(w1.x), wf = b2f(w1.y), wg = b2f(w1.z), wh = b2f(w1.w);
#pragma unroll
    for (int b = 0; b < 8; ++b) {
      const float* hr = hin + (size_t)(r0 + b) * 1024 + d0;
      float4 h0v = *(const float4*)hr;
      float4 h1v = *(const float4*)(hr + 4);
      acc[b] += wa*h0v.x + wb*h0v.y + wc*h0v.z + wd*h0v.w
              + we_*h1v.x + wf*h1v.y + wg*h1v.z + wh*h1v.w;
    }
    if (wrb) {
      ushort4 b0v = *(const ushort4*)(wrb + d0);
      ushort4 b1v = *(const ushort4*)(wrb + d0 + 4);
      float ba = b2f(b0v.x), bb = b2f(b0v.y), bcc = b2f(b0v.z), bd = b2f(b0v.w);
      float be = b2f(b1v.x), bfv = b2f(b1v.y), bg = b2f(b1v.z), bh = b2f(b1v.w);
#pragma unroll
      for (int b = 0; b < 8; ++b) {
        int rr = r0 + b;
        int ar = nr64 ? (((rr >> 3) << 6) + (acA << 3) + (rr & 7)) : rr;
        const float* pr = adA + (size_t)ar * 1024 + d0;
        float4 a0v = *(const float4*)pr;
        float4 a1v = *(const float4*)(pr + 4);
        acc[b] += ba*a0v.x + bb*a0v.y + bcc*a0v.z + bd*a0v.w
                + be*a1v.x + bfv*a1v.y + bg*a1v.z + bh*a1v.w;
      }
    }
  }
#pragma unroll
  for (int m = 1; m < 16; m <<= 1)
#pragma unroll
    for (int b = 0; b < 8; ++b) acc[b] += __shfl_xor(acc[b], m);
  if (lg == 0) {
#pragma unroll
    for (int b = 0; b < 8; ++b) {
      int rr = r0 + b;
      int ai = nr64 ? (((rr >> 3) << 6) + (acB << 3) + (rr & 7)) : rr;
      float v = acc[b] + adB[(size_t)ai * 1024 + e];
      ho[(size_t)rr * 1024 + e] = v;
      if (hb) {
        int bi = nr64 ? (((rr >> 3) << 6) + (bc << 3) + (rr & 7)) : rr;
        hb[(size_t)bi * 1024 + e] = f2b(v);
      }
    }
  }
}

// ---- power iteration + misc helpers -----------------------------------------
__global__ void k_init(const float* __restrict__ u_in, const float* __restrict__ h0,
                       float* __restrict__ u_cur, float* __restrict__ v_acc,
                       float* __restrict__ u_acc, float* __restrict__ hall0,
                       float* __restrict__ bndS, u16* __restrict__ bndb)
{
  int i = blockIdx.x * 256 + threadIdx.x;
  if (i < 1024) { u_cur[i] = u_in[i]; v_acc[i] = 0.f; u_acc[i] = 0.f; }
  if (i < 8192) { float h = h0[i]; hall0[i] = h; bndS[i] = h; bndb[i] = f2b(h); }
}

__global__ void k_v(const float* __restrict__ W, const float* __restrict__ u_cur,
                    float* __restrict__ v_acc)
{
  int d = blockIdx.x * 256 + threadIdx.x;
  int e0 = blockIdx.y * 64;
  float a = 0.f;
  for (int e = e0; e < e0 + 64; ++e) a += W[(size_t)e * 1024 + d] * u_cur[e];
  atomicAdd(&v_acc[d], a);
}

__global__ void k_u(const float* __restrict__ W, const float* __restrict__ v_cur,
                    float* __restrict__ u_acc)
{
  int lg = threadIdx.x & 15, ei = threadIdx.x >> 4;
  int e = blockIdx.y * 16 + ei;
  int d0 = blockIdx.x * 512;
  float a = 0.f;
  for (int i = 0; i < 32; ++i) { int d = d0 + lg + 16 * i; a += W[(size_t)e * 1024 + d] * v_cur[d]; }
#pragma unroll
  for (int m = 1; m < 16; m <<= 1) a += __shfl_xor(a, m);
  if (lg == 0) atomicAdd(&u_acc[e], a);
}

__global__ void k_norm(const float* __restrict__ acc, float* __restrict__ outv,
                       float* __restrict__ z1)
{
  __shared__ float red[16];
  int t = threadIdx.x;
  float x = acc[t];
  float ss = x * x;
#pragma unroll
  for (int m = 1; m < 64; m <<= 1) ss += __shfl_xor(ss, m);
  if ((t & 63) == 0) red[t >> 6] = ss;
  __syncthreads();
  if (t < 64) {
    float s = (t < 16) ? red[t] : 0.f;
#pragma unroll
    for (int m = 1; m < 16; m <<= 1) s += __shfl_xor(s, m);
    if (t == 0) red[0] = s;
  }
  __syncthreads();
  float nrm = sqrtf(red[0]) + 1e-8f;
  outv[t] = x / nrm;
  z1[t] = 0.f;
}

__global__ void k_sigma(const float* __restrict__ acc, float* __restrict__ scale)
{
  __shared__ float red[16];
  int t = threadIdx.x;
  float x = acc[t];
  float ss = x * x;
#pragma unroll
  for (int m = 1; m < 64; m <<= 1) ss += __shfl_xor(ss, m);
  if ((t & 63) == 0) red[t >> 6] = ss;
  __syncthreads();
  if (t < 64) {
    float s = (t < 16) ? red[t] : 0.f;
#pragma unroll
    for (int m = 1; m < 16; m <<= 1) s += __shfl_xor(s, m);
    if (t == 0) {
      float sigma = s / (sqrtf(s) + 1e-8f);
      scale[0] = 0.95f / (sigma + 1e-8f);
    }
  }
}

// Wh_bf16, Wh^T_bf16, and Bcat slot 3 (cols 3072..4095)
__global__ void k_scale(const float* __restrict__ W, const float* __restrict__ scale,
                        u16* __restrict__ wb, u16* __restrict__ wbT,
                        u16* __restrict__ bcat)
{
  int i = blockIdx.x * 256 + threadIdx.x;
  float v = W[i] * scale[0];
  u16 h = f2b(v);
  int e = i >> 10, d = i & 1023;
  wb[i] = h;
  wbT[(size_t)d * 1024 + e] = h;
  bcat[(size_t)e * 4096 + 3072 + d] = h;
}

__global__ void k_cvt(const float* __restrict__ in, u16* __restrict__ out, int n)
{
  int i = (blockIdx.x * 256 + threadIdx.x) * 4;
  if (i >= n) return;
  float4 v = *(const float4*)(in + i);
  ushort4 o;
  o.x = f2b(v.x); o.y = f2b(v.y); o.z = f2b(v.z); o.w = f2b(v.w);
  *(ushort4*)(out + i) = o;
}

// lam0[s*8+b] = lC row s*64+b  (Lambda_1)
__global__ void k_gather(const float* __restrict__ lC, float* __restrict__ lam0)
{
  int i = blockIdx.x * 256 + threadIdx.x;   // 64 blocks
  int r = i >> 8;
  int e4 = (i & 255) * 4;
  int src = ((r >> 3) << 6) + (r & 7);
  *(float4*)(lam0 + (size_t)r * 1024 + e4) = *(const float4*)(lC + (size_t)src * 1024 + e4);
}

extern "C" void kernel_launch(void* const* d_in, const int* in_sizes, int n_in,
                              void* d_out, int out_size, void* d_ws, size_t ws_size,
                              hipStream_t stream)
{
  (void)in_sizes; (void)n_in; (void)out_size; (void)ws_size;
  const float* x  = (const float*)d_in[0];   // [2048,8,1024]
  const float* h0 = (const float*)d_in[1];   // [8,1024]
  const float* Wx = (const float*)d_in[2];   // [1024,1024]
  const float* Wh = (const float*)d_in[3];   // [1024,1024]
  const float* bv = (const float*)d_in[4];   // [1024]
  const float* uv = (const float*)d_in[5];   // [1024]

  float* out0 = (float*)d_out;               // [2048,8,1024]
  float* hall = out0 + 16777216;             // [2049,8,1024]

  // ---- ws layout (all read during phase 3 or small state) ----
  char* ws = (char*)d_ws;
  u16*   pre_b = (u16*)(ws);                  // 32 MB [16384,1024] bf16
  u16*   Bcat  = (u16*)(ws + 33554432);       // 8 MB  [1024,4096]: W4|W3|W2|W
  u16*   lb0   = (u16*)(ws + 41943040);       // 1 MB chain ping
  u16*   lb1   = (u16*)(ws + 42991616);       // 1 MB chain pong
  u16*   bnd_b = (u16*)(ws + 44040192);       // 1 MB [512,1024] chunk boundaries bf16
  float* lC    = (float*)(ws + 45088768);     // 2 MB [512,1024] fp32 chunk finals
  float* lam0  = (float*)(ws + 47185920);     // 256 KB
  float* lam1  = (float*)(ws + 47448064);     // 256 KB
  float* bndS  = (float*)(ws + 47710208);     // 256 KB superchunk boundaries fp32
  float* pc0   = (float*)(ws + 47972352);     // 256 KB
  float* pc1   = (float*)(ws + 48234496);     // 256 KB
  float* dumv  = (float*)(ws + 48496640);     // 256 KB dummy sink
  float* u_cur = (float*)(ws + 48758784);
  float* v_cur = u_cur + 1024;
  float* v_acc = u_cur + 2048;
  float* u_acc = u_cur + 3072;
  float* scale = u_cur + 4096;

  // ---- scratch inside d_out (dead before the phases that overwrite it) ----
  u16*  xb = (u16*)d_out;                     // x bf16, first 32 MB of out0
  char* HB = (char*)hall;                     // hall region scratch (dead until phase 3)
  u16* wh_b  = (u16*)(HB + 16777216);
  u16* whT_b = (u16*)(HB + 18874368);
  u16* wxb   = (u16*)(HB + 20971520);
  u16* P0    = (u16*)(HB + 23068672);
  u16* P0T   = (u16*)(HB + 25165824);
  u16* P1    = (u16*)(HB + 27262976);
  u16* P1T   = (u16*)(HB + 29360128);
  u16* W32   = (u16*)(HB + 31457280);
  u16* W64   = (u16*)(HB + 33554432);
  u16* W256  = (u16*)(HB + 35651584);
  u16* W512  = (u16*)(HB + 37748736);

  const u16* NU = nullptr; u16* NUo = nullptr; float* NUf = nullptr;

  k_init<<<32, 256, 0, stream>>>(uv, h0, u_cur, v_acc, u_acc, hall, bndS, bnd_b);

  for (int it = 0; it < 3; ++it) {
    k_v<<<dim3(4, 16), 256, 0, stream>>>(Wh, u_cur, v_acc);
    k_norm<<<1, 1024, 0, stream>>>(v_acc, v_cur, u_acc);
    k_u<<<dim3(2, 64), 256, 0, stream>>>(Wh, v_cur, u_acc);
    if (it < 2) k_norm<<<1, 1024, 0, stream>>>(u_acc, u_cur, v_acc);
    else        k_sigma<<<1, 1024, 0, stream>>>(u_acc, scale);
  }
  k_scale<<<4096, 256, 0, stream>>>(Wh, scale, wh_b, whT_b, Bcat);

  k_cvt<<<16384, 256, 0, stream>>>(x, xb, 16777216);
  k_cvt<<<1024, 256, 0, stream>>>(Wx, wxb, 1048576);

  // pre = x @ Wx^T + b
  gK<0><<<dim3(16, 256), 256, 0, stream>>>(xb, NU, 0, 0u, 1, 0, wxb, 1024,
                                           bv, 0, pre_b, NUo, NUo, 0, NUf, NUf, 0);

  // ---- Wh powers (A*B^T form, carrying transposes) ----
  // S1: W2
  gK<1><<<dim3(16, 16), 256, 0, stream>>>(wh_b, NU, 0, 0u, 1, 0, whT_b, 1024,
                                          nullptr, 0, P0, P0T, Bcat, 2048, NUf, NUf, 0);
  // S2a: W3 -> Bcat slot1 only
  gK<1><<<dim3(16, 16), 256, 0, stream>>>(P0, NU, 0, 0u, 1, 0, whT_b, 1024,
                                          nullptr, 0, NUo, NUo, Bcat, 1024, NUf, NUf, 0);
  // S2b: W4
  gK<1><<<dim3(16, 16), 256, 0, stream>>>(P0, NU, 0, 0u, 1, 0, P0T, 1024,
                                          nullptr, 0, P1, P1T, Bcat, 0, NUf, NUf, 0);
  // S3: W8 = W4*W4
  gK<1><<<dim3(16, 16), 256, 0, stream>>>(P1, NU, 0, 0u, 1, 0, P1T, 1024,
                                          nullptr, 0, P0, P0T, NUo, 0, NUf, NUf, 0);
  // S4: W16
  gK<1><<<dim3(16, 16), 256, 0, stream>>>(P0, NU, 0, 0u, 1, 0, P0T, 1024,
                                          nullptr, 0, P1, P1T, NUo, 0, NUf, NUf, 0);
  // S5: W32 (T in P0T)
  gK<1><<<dim3(16, 16), 256, 0, stream>>>(P1, NU, 0, 0u, 1, 0, P1T, 1024,
                                          nullptr, 0, W32, P0T, NUo, 0, NUf, NUf, 0);
  // S6: W64 (T in P1T)
  gK<1><<<dim3(16, 16), 256, 0, stream>>>(W32, NU, 0, 0u, 1, 0, P0T, 1024,
                                          nullptr, 0, W64, P1T, NUo, 0, NUf, NUf, 0);
  // S7: W128 -> P0/P0T
  gK<1><<<dim3(16, 16), 256, 0, stream>>>(W64, NU, 0, 0u, 1, 0, P1T, 1024,
                                          nullptr, 0, P0, P0T, NUo, 0, NUf, NUf, 0);
  // S8: W256 (T in P1T)
  gK<1><<<dim3(16, 16), 256, 0, stream>>>(P0, NU, 0, 0u, 1, 0, P0T, 1024,
                                          nullptr, 0, W256, P1T, NUo, 0, NUf, NUf, 0);
  // S9: W512
  gK<1><<<dim3(16, 16), 256, 0, stream>>>(W256, NU, 0, 0u, 1, 0, P1T, 1024,
                                          nullptr, 0, W512, NUo, NUo, 0, NUf, NUf, 0);

  // ---- phase 1: 8 quad-steps; l_{c+4} = W4 l_c + W3 p_c + W2 p_{c+1} + W p_{c+2} + p_{c+3}
  for (int k = 1; k <= 8; ++k) {
    int c = 4 * (k - 1);
    u16* out = (k & 1) ? lb0 : lb1;
    const u16* in = ((k - 1) & 1) ? lb0 : lb1;   // out of k-1
    if (k == 1)
      gK<2><<<dim3(16, 8), 256, 0, stream>>>(NU, pre_b, 0, 0x7u, 3, 1024, Bcat, 4096,
                                             nullptr, 3, out, NUo, NUo, 0, NUf, NUf, 0);
    else
      gK<2><<<dim3(16, 8), 256, 0, stream>>>(in, pre_b, c - 1, 0xEu, 4, 0, Bcat, 4096,
                                             nullptr, c + 3, out, NUo, NUo, 0,
                                             (k == 8) ? lC : NUf, NUf, 0);
  }

  // ---- gather Lambda_1 ----
  k_gather<<<64, 256, 0, stream>>>(lC, lam0);

  // ---- phase 2a: Lambda 1->3->5->7->8 (3x mv2 + 1x mv1) ----
  mv_flex<<<dim3(64, 8, 1), 256, 0, stream>>>(
      lam0, W64, W32, lC, lC, lam1, NUo, 1, 2, 0,
      NUf, NU, NU, NUf, NUf, NUf, NUo, 0, 0, 0, 1);
  mv_flex<<<dim3(64, 8, 1), 256, 0, stream>>>(
      lam1, W64, W32, lC, lC, lam0, NUo, 3, 4, 0,
      NUf, NU, NU, NUf, NUf, NUf, NUo, 0, 0, 0, 1);
  mv_flex<<<dim3(64, 8, 1), 256, 0, stream>>>(
      lam0, W64, W32, lC, lC, lam1, NUo, 5, 6, 0,
      NUf, NU, NU, NUf, NUf, NUf, NUo, 0, 0, 0, 1);
  mv_flex<<<dim3(64, 8, 1), 256, 0, stream>>>(
      lam1, W32, NU, NUf, lC, lam0, NUo, 0, 7, 0,
      NUf, NU, NU, NUf, NUf, NUf, NUo, 0, 0, 0, 1);
  // Lambda_8 in lam0 (rows s*8+b)

  // ---- phase 2b: superchunk chain b0->(b1,b2)->(b3,b4)->(b5,b6)->b7 ----
  for (int s = 0; s < 3; ++s) {
    float* bs = bndS + (size_t)2 * s * 8192;
    mv_flex<<<dim3(64, 1, 2), 256, 0, stream>>>(
        bs, W256, NU, NUf, lam0 + (size_t)2 * s * 8192,
        bs + 8192, bnd_b + (size_t)(2 * s + 1) * 65536, 0, 0, 0,
        bs, W512, W256, lam0 + (size_t)2 * s * 8192, lam0 + (size_t)(2 * s + 1) * 8192,
        bs + 16384, bnd_b + (size_t)(2 * s + 2) * 65536, 0, 0, 0, 0);
  }
  mv_flex<<<dim3(64, 1, 1), 256, 0, stream>>>(
      bndS + (size_t)6 * 8192, W256, NU, NUf, lam0 + (size_t)6 * 8192,
      bndS + (size_t)7 * 8192, bnd_b + (size_t)7 * 65536, 0, 0, 0,
      NUf, NU, NU, NUf, NUf, NUf, NUo, 0, 0, 0, 0);

  // ---- phase 2c: intra-super boundaries c=1..7 (pairs) ----
  mv_flex<<<dim3(64, 8, 2), 256, 0, stream>>>(
      bndS, W32, NU, NUf, lC, dumv, bnd_b, 0, 0, 1,
      bndS, W64, W32, lC, lC, pc0, bnd_b, 0, 1, 2, 1);
  mv_flex<<<dim3(64, 8, 2), 256, 0, stream>>>(
      pc0, W32, NU, NUf, lC, dumv, bnd_b, 0, 2, 3,
      pc0, W64, W32, lC, lC, pc1, bnd_b, 2, 3, 4, 1);
  mv_flex<<<dim3(64, 8, 2), 256, 0, stream>>>(
      pc1, W32, NU, NUf, lC, dumv, bnd_b, 0, 4, 5,
      pc1, W64, W32, lC, lC, pc0, bnd_b, 4, 5, 6, 1);
  mv_flex<<<dim3(64, 8, 1), 256, 0, stream>>>(
      pc0, W32, NU, NUf, lC, dumv, bnd_b, 0, 6, 7,
      NUf, NU, NU, NUf, NUf, NUf, NUo, 0, 0, 0, 1);

  // ---- phase 3: 8 quad-steps, z=q-1 in {0..3}; fused h_all + h^2*silu ----
  for (int k = 0; k <= 7; ++k) {
    int c = 4 * k;
    const u16* in = (k == 0) ? bnd_b : ((k & 1) ? lb0 : lb1);
    u16* out = (k & 1) ? lb1 : lb0;
    gK<3><<<dim3(16, 8, 4), 256, 0, stream>>>(in, pre_b, c - 1, 0xEu, 0, 0, Bcat, 4096,
                                              nullptr, 0, out, NUo, NUo, 0,
                                              hall, out0, c);
  }
}